// Round 1
// baseline (470.451 us; speedup 1.0000x reference)
//
#include <hip/hip_runtime.h>
#include <math.h>

// Problem constants (from reference): N=16, V=4096, I=128, O=128, G=16
#define NN 16
#define VV 4096
#define II 128
#define OO 128
#define GG 16

// One block per v. 256 threads: o = tid&127, nh = tid>>7 (each thread does 8 n-rows).
// fp32 baseline: lin_x as per-thread dot products over i, x staged in LDS
// (wave-uniform broadcast reads), weights as float4 global loads (L2-served).
__global__ __launch_bounds__(256, 4) void ggru_fp32_kernel(
    const float* __restrict__ x,     // (N,V,I)
    const float* __restrict__ hx,    // (N,V,O)
    const int*   __restrict__ gidx,  // (V,)
    const float* __restrict__ w_ih,  // (3,G,O,I)
    const float* __restrict__ b_ih,  // (3,G,O)
    const float* __restrict__ w_hh,  // (3,G,O,O)
    const float* __restrict__ b_hh,  // (3,G,O)
    float*       __restrict__ out)   // (N,V,O)
{
    const int v   = blockIdx.x;
    const int tid = threadIdx.x;
    const int o   = tid & 127;
    const int nh  = tid >> 7;      // 0 or 1
    const int nbase = nh * 8;
    const int g   = gidx[v];

    __shared__ float xs[NN][II];   // 8 KB

    // Cooperative load of x[:, v, :] -> LDS. 2048 floats / 256 threads = 8 each.
    {
        const int f  = tid * 8;
        const int n0 = f >> 7;     // row in [0,16)
        const int i0 = f & 127;
        const float* src = x + ((size_t)n0 * VV + v) * II + i0;
        float4 a = *(const float4*)(src);
        float4 b = *(const float4*)(src + 4);
        *(float4*)&xs[n0][i0]     = a;
        *(float4*)&xs[n0][i0 + 4] = b;
    }
    __syncthreads();

    float acc0[8], acc1[8], acc2[8];
    #pragma unroll
    for (int n = 0; n < 8; ++n) { acc0[n] = 0.f; acc1[n] = 0.f; acc2[n] = 0.f; }

    const float* w0p = w_ih + ((size_t)(0 * GG + g) * OO + o) * II;
    const float* w1p = w_ih + ((size_t)(1 * GG + g) * OO + o) * II;
    const float* w2p = w_ih + ((size_t)(2 * GG + g) * OO + o) * II;

    // Main loop: 32 chunks of 4 i's. Per chunk: 3x global dwordx4 (weights),
    // 8x ds_read_b128 (x, wave-uniform broadcast), 96 FMA.
    for (int i = 0; i < II; i += 4) {
        const float4 w0 = *(const float4*)(w0p + i);
        const float4 w1 = *(const float4*)(w1p + i);
        const float4 w2 = *(const float4*)(w2p + i);
        #pragma unroll
        for (int n = 0; n < 8; ++n) {
            const float4 xv = *(const float4*)&xs[nbase + n][i];
            acc0[n] = fmaf(w0.x, xv.x, acc0[n]);
            acc0[n] = fmaf(w0.y, xv.y, acc0[n]);
            acc0[n] = fmaf(w0.z, xv.z, acc0[n]);
            acc0[n] = fmaf(w0.w, xv.w, acc0[n]);
            acc1[n] = fmaf(w1.x, xv.x, acc1[n]);
            acc1[n] = fmaf(w1.y, xv.y, acc1[n]);
            acc1[n] = fmaf(w1.z, xv.z, acc1[n]);
            acc1[n] = fmaf(w1.w, xv.w, acc1[n]);
            acc2[n] = fmaf(w2.x, xv.x, acc2[n]);
            acc2[n] = fmaf(w2.y, xv.y, acc2[n]);
            acc2[n] = fmaf(w2.z, xv.z, acc2[n]);
            acc2[n] = fmaf(w2.w, xv.w, acc2[n]);
        }
    }

    // Epilogue: biases, diagonal lin_h, gates, output.
    const float bi0 = b_ih[(0 * GG + g) * OO + o];
    const float bi1 = b_ih[(1 * GG + g) * OO + o];
    const float bi2 = b_ih[(2 * GG + g) * OO + o];
    const float bh0 = b_hh[(0 * GG + g) * OO + o];
    const float bh1 = b_hh[(1 * GG + g) * OO + o];
    const float bh2 = b_hh[(2 * GG + g) * OO + o];
    const float wd0 = w_hh[((size_t)(0 * GG + g) * OO + o) * OO + o];
    const float wd1 = w_hh[((size_t)(1 * GG + g) * OO + o) * OO + o];
    const float wd2 = w_hh[((size_t)(2 * GG + g) * OO + o) * OO + o];

    #pragma unroll
    for (int n = 0; n < 8; ++n) {
        const int nn = nbase + n;
        const size_t idx = ((size_t)nn * VV + v) * OO + o;
        const float h = hx[idx];

        const float gr = acc0[n] + bi0 + fmaf(h, wd0, bh0);
        const float gz = acc1[n] + bi1 + fmaf(h, wd1, bh1);
        const float ghn = fmaf(h, wd2, bh2);

        const float r = 1.f / (1.f + __expf(-gr));
        const float z = 1.f / (1.f + __expf(-gz));

        float t = acc2[n] + bi2 + r * ghn;
        // safe tanh: clamp so exp doesn't overflow to inf (NaN guard)
        t = fminf(fmaxf(t, -15.f), 15.f);
        const float e2 = __expf(2.f * t);
        const float th = (e2 - 1.f) / (e2 + 1.f);

        out[idx] = (1.f - z) * th + z * h;
    }
}

extern "C" void kernel_launch(void* const* d_in, const int* in_sizes, int n_in,
                              void* d_out, int out_size, void* d_ws, size_t ws_size,
                              hipStream_t stream) {
    const float* x    = (const float*)d_in[0];
    const float* hx   = (const float*)d_in[1];
    const int*   gidx = (const int*)d_in[2];
    const float* w_ih = (const float*)d_in[3];
    const float* b_ih = (const float*)d_in[4];
    const float* w_hh = (const float*)d_in[5];
    const float* b_hh = (const float*)d_in[6];
    float* out = (float*)d_out;

    ggru_fp32_kernel<<<VV, 256, 0, stream>>>(x, hx, gidx, w_ih, b_ih, w_hh, b_hh, out);
}

// Round 6
// 176.910 us; speedup vs baseline: 2.6593x; 2.6593x over previous
//
#include <hip/hip_runtime.h>
#include <math.h>

// Problem constants: N=16, V=4096, I=128, O=128, G=16
#define NN 16
#define VV 4096
#define II 128
#define OO 128
#define GG 16

typedef __attribute__((ext_vector_type(8))) short bf16x8;
typedef __attribute__((ext_vector_type(4))) float f32x4;

__device__ inline unsigned short f2bf(float f) {
    union { float f; unsigned u; } c; c.f = f;
    unsigned r = c.u + 0x7FFFu + ((c.u >> 16) & 1u);
    return (unsigned short)(r >> 16);
}
__device__ inline float bf2f(unsigned short h) {
    union { unsigned u; float f; } c; c.u = ((unsigned)h) << 16;
    return c.f;
}
// split one float into bf16 hi + bf16 lo (x ~= hi + lo, ~2^-17 rel)
__device__ inline void split1(float f, unsigned short& hi, unsigned short& lo) {
    hi = f2bf(f);
    lo = f2bf(f - bf2f(hi));
}
__device__ inline bf16x8 as_bf(uint4 u) {
    union { uint4 u; bf16x8 b; } c; c.u = u; return c.b;
}
__device__ inline void pack8(const float4& a, const float4& b, uint4& ph, uint4& pl) {
    unsigned short hi[8], lo[8];
    split1(a.x, hi[0], lo[0]); split1(a.y, hi[1], lo[1]);
    split1(a.z, hi[2], lo[2]); split1(a.w, hi[3], lo[3]);
    split1(b.x, hi[4], lo[4]); split1(b.y, hi[5], lo[5]);
    split1(b.z, hi[6], lo[6]); split1(b.w, hi[7], lo[7]);
    ph.x = (unsigned)hi[0] | ((unsigned)hi[1] << 16);
    ph.y = (unsigned)hi[2] | ((unsigned)hi[3] << 16);
    ph.z = (unsigned)hi[4] | ((unsigned)hi[5] << 16);
    ph.w = (unsigned)hi[6] | ((unsigned)hi[7] << 16);
    pl.x = (unsigned)lo[0] | ((unsigned)lo[1] << 16);
    pl.y = (unsigned)lo[2] | ((unsigned)lo[3] << 16);
    pl.z = (unsigned)lo[4] | ((unsigned)lo[5] << 16);
    pl.w = (unsigned)lo[6] | ((unsigned)lo[7] << 16);
}

// ---------------------------------------------------------------------------
// Pre-pack w_ih (3,G,O,I) fp32 -> split-bf16 MFMA B-fragments in d_ws.
// pair index pidx = (((gate*16+g)*8 + ct)*4 + s)*64 + lane
//   holds w[gate][g][o=ct*16+(lane&15)][i=s*32+(lane>>4)*8+j], j=0..7
// hi uint4 at wp[pidx*2], lo at wp[pidx*2+1]. 98304 pairs = 3 MB.
// ---------------------------------------------------------------------------
__global__ __launch_bounds__(256) void prepack_kernel(
    const float* __restrict__ w_ih, uint4* __restrict__ wp)
{
    const int t  = blockIdx.x * 256 + threadIdx.x;   // [0, 98304)
    const int i8 = t & 15;          // i-block of 8 (fastest -> coalesced)
    const int o  = (t >> 4) & 127;
    const int gg = t >> 11;         // gate*16+g in [0,48)

    const float* src = w_ih + ((size_t)gg * OO + o) * II + i8 * 8;
    const float4 a = *(const float4*)src;
    const float4 b = *(const float4*)(src + 4);
    uint4 ph, pl;
    pack8(a, b, ph, pl);

    const int s    = i8 >> 2;
    const int kb   = i8 & 3;
    const int lane = kb * 16 + (o & 15);
    const int ct   = o >> 4;
    const int pidx = ((gg * 8 + ct) * 4 + s) * 64 + lane;
    wp[pidx * 2]     = ph;
    wp[pidx * 2 + 1] = pl;
}

// ---------------------------------------------------------------------------
// Main: one block per v. 4 waves; wave wv owns 6 col-tiles of the stacked
// (3 gates x 128 o) = 384-col pre-activation GEMM (16 x 384, K=128),
// split-bf16 x3 MFMA (xh*wh + xl*wh + xh*wl) for fp32-like accuracy.
// PREPACKED=1: weights from d_ws fragments; PREPACKED=0: convert inline.
// ---------------------------------------------------------------------------
template <bool PREPACKED>
__global__ __launch_bounds__(256, 4) void ggru_mfma_kernel(
    const float* __restrict__ x,     // (N,V,I)
    const float* __restrict__ hx,    // (N,V,O)
    const int*   __restrict__ gidx,  // (V,)
    const uint4* __restrict__ wp,    // packed w_ih fragments (PREPACKED)
    const float* __restrict__ w_ih,  // raw w_ih (fallback)
    const float* __restrict__ b_ih,  // (3,G,O)
    const float* __restrict__ w_hh,  // (3,G,O,O)
    const float* __restrict__ b_hh,  // (3,G,O)
    float*       __restrict__ out)   // (N,V,O)
{
    const int v    = blockIdx.x;
    const int tid  = threadIdx.x;
    const int lane = tid & 63;
    const int wv   = tid >> 6;
    const int g    = gidx[v];

    __shared__ uint4 xhS[256];             // A-frags hi: idx = s*64 + lane
    __shared__ uint4 xlS[256];             // A-frags lo
    __shared__ float gbuf[3][NN][132];     // padded stride vs bank aliasing

    // ---- stage x[:, v, :] as split-bf16 A-fragments ----
    {
        const int row = tid >> 4;          // 0..15
        const int sk  = tid & 15;
        const int s   = sk >> 2, kb = sk & 3;
        const float* xp = x + ((size_t)row * VV + v) * II + s * 32 + kb * 8;
        const float4 xa = *(const float4*)xp;
        const float4 xb = *(const float4*)(xp + 4);
        uint4 ph, pl;
        pack8(xa, xb, ph, pl);
        xhS[s * 64 + kb * 16 + row] = ph;
        xlS[s * 64 + kb * 16 + row] = pl;
    }
    __syncthreads();

    // ---- per-wave tile bases ----
    int tb[6];
    const float* wraw[6];
    #pragma unroll
    for (int t = 0; t < 6; ++t) {
        const int col  = wv * 96 + t * 16;
        const int gate = col >> 7;
        const int ob   = col & 127;
        const int ct   = ob >> 4;
        tb[t] = ((gate * GG + g) * 8 + ct) * 4;
        wraw[t] = w_ih + (((size_t)gate * GG + g) * OO + ob + (lane & 15)) * II + (lane >> 4) * 8;
    }

    f32x4 acc[6];
    #pragma unroll
    for (int t = 0; t < 6; ++t) acc[t] = (f32x4){0.f, 0.f, 0.f, 0.f};

    #pragma unroll
    for (int s = 0; s < 4; ++s) {
        const bf16x8 ah = as_bf(xhS[s * 64 + lane]);
        const bf16x8 al = as_bf(xlS[s * 64 + lane]);
        #pragma unroll
        for (int t = 0; t < 6; ++t) {
            bf16x8 wh, wl;
            if (PREPACKED) {
                wh = as_bf(wp[(size_t)(tb[t] + s) * 128 + lane * 2]);
                wl = as_bf(wp[(size_t)(tb[t] + s) * 128 + lane * 2 + 1]);
            } else {
                const float4 wa = *(const float4*)(wraw[t] + s * 32);
                const float4 wb = *(const float4*)(wraw[t] + s * 32 + 4);
                uint4 ph, pl;
                pack8(wa, wb, ph, pl);
                wh = as_bf(ph);
                wl = as_bf(pl);
            }
            acc[t] = __builtin_amdgcn_mfma_f32_16x16x32_bf16(ah, wh, acc[t], 0, 0, 0);
            acc[t] = __builtin_amdgcn_mfma_f32_16x16x32_bf16(al, wh, acc[t], 0, 0, 0);
            acc[t] = __builtin_amdgcn_mfma_f32_16x16x32_bf16(ah, wl, acc[t], 0, 0, 0);
        }
    }

    // ---- scatter pre-activations (C/D: col=lane&15, row=(lane>>4)*4+r) ----
    #pragma unroll
    for (int t = 0; t < 6; ++t) {
        const int col  = wv * 96 + t * 16 + (lane & 15);
        const int gate = col >> 7;
        const int o    = col & 127;
        #pragma unroll
        for (int r = 0; r < 4; ++r) {
            gbuf[gate][(lane >> 4) * 4 + r][o] = acc[t][r];
        }
    }
    __syncthreads();

    // ---- epilogue (same math as R0-verified, absmax 0.0078) ----
    {
        const int o  = tid & 127;
        const int rb = (tid >> 7) * 8;

        const float bi0 = b_ih[(0 * GG + g) * OO + o];
        const float bi1 = b_ih[(1 * GG + g) * OO + o];
        const float bi2 = b_ih[(2 * GG + g) * OO + o];
        const float bh0 = b_hh[(0 * GG + g) * OO + o];
        const float bh1 = b_hh[(1 * GG + g) * OO + o];
        const float bh2 = b_hh[(2 * GG + g) * OO + o];
        const float wd0 = w_hh[((size_t)(0 * GG + g) * OO + o) * OO + o];
        const float wd1 = w_hh[((size_t)(1 * GG + g) * OO + o) * OO + o];
        const float wd2 = w_hh[((size_t)(2 * GG + g) * OO + o) * OO + o];

        #pragma unroll
        for (int r = 0; r < 8; ++r) {
            const int row = rb + r;
            const size_t idx = ((size_t)row * VV + v) * OO + o;
            const float h = hx[idx];

            const float gr  = gbuf[0][row][o] + bi0 + fmaf(h, wd0, bh0);
            const float gz  = gbuf[1][row][o] + bi1 + fmaf(h, wd1, bh1);
            const float ghn = fmaf(h, wd2, bh2);

            const float rr = 1.f / (1.f + __expf(-gr));
            const float zz = 1.f / (1.f + __expf(-gz));

            float t = gbuf[2][row][o] + bi2 + rr * ghn;
            t = fminf(fmaxf(t, -15.f), 15.f);
            const float e2 = __expf(2.f * t);
            const float th = (e2 - 1.f) / (e2 + 1.f);

            out[idx] = (1.f - zz) * th + zz * h;
        }
    }
}

extern "C" void kernel_launch(void* const* d_in, const int* in_sizes, int n_in,
                              void* d_out, int out_size, void* d_ws, size_t ws_size,
                              hipStream_t stream) {
    const float* x    = (const float*)d_in[0];
    const float* hx   = (const float*)d_in[1];
    const int*   gidx = (const int*)d_in[2];
    const float* w_ih = (const float*)d_in[3];
    const float* b_ih = (const float*)d_in[4];
    const float* w_hh = (const float*)d_in[5];
    const float* b_hh = (const float*)d_in[6];
    float* out = (float*)d_out;
    uint4* wp  = (uint4*)d_ws;   // 3 MB packed split-bf16 w_ih fragments

    const size_t need = 98304ull * 32ull;   // 3 MB
    if (ws_size >= need) {
        prepack_kernel<<<384, 256, 0, stream>>>(w_ih, wp);
        ggru_mfma_kernel<true><<<VV, 256, 0, stream>>>(
            x, hx, gidx, wp, w_ih, b_ih, w_hh, b_hh, out);
    } else {
        ggru_mfma_kernel<false><<<VV, 256, 0, stream>>>(
            x, hx, gidx, (const uint4*)nullptr, w_ih, b_ih, w_hh, b_hh, out);
    }
}

// Round 10
// 172.662 us; speedup vs baseline: 2.7247x; 1.0246x over previous
//
#include <hip/hip_runtime.h>
#include <math.h>

// Problem constants: N=16, V=4096, I=128, O=128, G=16
#define NN 16
#define VV 4096
#define II 128
#define OO 128
#define GG 16

typedef __attribute__((ext_vector_type(8))) short bf16x8;
typedef __attribute__((ext_vector_type(4))) float f32x4;

__device__ inline unsigned short f2bf(float f) {
    union { float f; unsigned u; } c; c.f = f;
    unsigned r = c.u + 0x7FFFu + ((c.u >> 16) & 1u);
    return (unsigned short)(r >> 16);
}
__device__ inline float bf2f(unsigned short h) {
    union { unsigned u; float f; } c; c.u = ((unsigned)h) << 16;
    return c.f;
}
// split one float into bf16 hi + bf16 lo (x ~= hi + lo, ~2^-17 rel)
__device__ inline void split1(float f, unsigned short& hi, unsigned short& lo) {
    hi = f2bf(f);
    lo = f2bf(f - bf2f(hi));
}
__device__ inline bf16x8 as_bf(uint4 u) {
    union { uint4 u; bf16x8 b; } c; c.u = u; return c.b;
}
__device__ inline void pack8(const float4& a, const float4& b, uint4& ph, uint4& pl) {
    unsigned short hi[8], lo[8];
    split1(a.x, hi[0], lo[0]); split1(a.y, hi[1], lo[1]);
    split1(a.z, hi[2], lo[2]); split1(a.w, hi[3], lo[3]);
    split1(b.x, hi[4], lo[4]); split1(b.y, hi[5], lo[5]);
    split1(b.z, hi[6], lo[6]); split1(b.w, hi[7], lo[7]);
    ph.x = (unsigned)hi[0] | ((unsigned)hi[1] << 16);
    ph.y = (unsigned)hi[2] | ((unsigned)hi[3] << 16);
    ph.z = (unsigned)hi[4] | ((unsigned)hi[5] << 16);
    ph.w = (unsigned)hi[6] | ((unsigned)hi[7] << 16);
    pl.x = (unsigned)lo[0] | ((unsigned)lo[1] << 16);
    pl.y = (unsigned)lo[2] | ((unsigned)lo[3] << 16);
    pl.z = (unsigned)lo[4] | ((unsigned)lo[5] << 16);
    pl.w = (unsigned)lo[6] | ((unsigned)lo[7] << 16);
}

// ---------------------------------------------------------------------------
// Pre-pack w_ih (3,G,O,I) fp32 -> split-bf16 MFMA B-fragments in d_ws.
// pair index pidx = (((gate*16+g)*8 + ct)*4 + s)*64 + lane
//   holds w[gate][g][o=ct*16+(lane&15)][i=s*32+(lane>>4)*8+j], j=0..7
// hi uint4 at wp[pidx*2], lo at wp[pidx*2+1]. 98304 pairs = 3 MB.
// (HW-verified correct via the R6 passing run)
// ---------------------------------------------------------------------------
__global__ __launch_bounds__(256) void prepack_kernel(
    const float* __restrict__ w_ih, uint4* __restrict__ wp)
{
    const int t  = blockIdx.x * 256 + threadIdx.x;   // [0, 98304)
    const int i8 = t & 15;
    const int o  = (t >> 4) & 127;
    const int gg = t >> 11;

    const float* src = w_ih + ((size_t)gg * OO + o) * II + i8 * 8;
    const float4 a = *(const float4*)src;
    const float4 b = *(const float4*)(src + 4);
    uint4 ph, pl;
    pack8(a, b, ph, pl);

    const int s    = i8 >> 2;
    const int kb   = i8 & 3;
    const int lane = kb * 16 + (o & 15);
    const int ct   = o >> 4;
    const int pidx = ((gg * 8 + ct) * 4 + s) * 64 + lane;
    wp[pidx * 2]     = ph;
    wp[pidx * 2 + 1] = pl;
}

// ---------------------------------------------------------------------------
// Main v2: one block per v, 4 waves. Wave wv owns o-cols [wv*32, wv*32+32)
// of EACH of the 3 gates (6 tiles: ga x t). One lane therefore holds r/z/n
// accumulators for the same (row,o) -> epilogue fully in registers, no gbuf,
// no 2nd barrier, no LDS bank conflicts. Per s-step: batch all 12 weight
// fragment loads into regs, then 18 MFMAs (latency hiding via batch + TLP).
// ---------------------------------------------------------------------------
template <bool PREPACKED>
__global__ __launch_bounds__(256, 4) void ggru_mfma_kernel(
    const float* __restrict__ x,     // (N,V,I)
    const float* __restrict__ hx,    // (N,V,O)
    const int*   __restrict__ gidx,  // (V,)
    const uint4* __restrict__ wp,    // packed w_ih fragments (PREPACKED)
    const float* __restrict__ w_ih,  // raw w_ih (fallback)
    const float* __restrict__ b_ih,  // (3,G,O)
    const float* __restrict__ w_hh,  // (3,G,O,O)
    const float* __restrict__ b_hh,  // (3,G,O)
    float*       __restrict__ out)   // (N,V,O)
{
    const int v    = blockIdx.x;
    const int tid  = threadIdx.x;
    const int lane = tid & 63;
    const int wv   = tid >> 6;
    const int g    = gidx[v];

    __shared__ uint4 xhS[256];   // A-frags hi: idx = s*64 + lane (8 KB total LDS)
    __shared__ uint4 xlS[256];   // A-frags lo

    // ---- stage x[:, v, :] as split-bf16 A-fragments (same map as R5, HW-ok) ----
    {
        const int row = tid >> 4;          // 0..15
        const int sk  = tid & 15;
        const int s   = sk >> 2, kb = sk & 3;
        const float* xp = x + ((size_t)row * VV + v) * II + s * 32 + kb * 8;
        const float4 xa = *(const float4*)xp;
        const float4 xb = *(const float4*)(xp + 4);
        uint4 ph, pl;
        pack8(xa, xb, ph, pl);
        xhS[s * 64 + kb * 16 + row] = ph;
        xlS[s * 64 + kb * 16 + row] = pl;
    }
    __syncthreads();

    // ---- tile bases: gate ga, col-tile t -> ct = wv*2 + t in [0,8) ----
    int tb[3][2];
    const float* wraw[3][2];
    #pragma unroll
    for (int ga = 0; ga < 3; ++ga) {
        #pragma unroll
        for (int t = 0; t < 2; ++t) {
            const int ct = wv * 2 + t;
            tb[ga][t] = ((ga * GG + g) * 8 + ct) * 4;
            wraw[ga][t] = w_ih + (((size_t)ga * GG + g) * OO + ct * 16 + (lane & 15)) * II
                          + (lane >> 4) * 8;
        }
    }

    f32x4 acc[3][2];
    #pragma unroll
    for (int ga = 0; ga < 3; ++ga)
        #pragma unroll
        for (int t = 0; t < 2; ++t)
            acc[ga][t] = (f32x4){0.f, 0.f, 0.f, 0.f};

    #pragma unroll
    for (int s = 0; s < 4; ++s) {
        const bf16x8 ah = as_bf(xhS[s * 64 + lane]);
        const bf16x8 al = as_bf(xlS[s * 64 + lane]);

        // batch all 12 fragment loads first (12 outstanding loads/wave)
        uint4 wh6[6], wl6[6];
        if (PREPACKED) {
            #pragma unroll
            for (int ga = 0; ga < 3; ++ga) {
                #pragma unroll
                for (int t = 0; t < 2; ++t) {
                    const size_t base = (size_t)(tb[ga][t] + s) * 128 + lane * 2;
                    wh6[ga * 2 + t] = wp[base];
                    wl6[ga * 2 + t] = wp[base + 1];
                }
            }
        } else {
            #pragma unroll
            for (int ga = 0; ga < 3; ++ga) {
                #pragma unroll
                for (int t = 0; t < 2; ++t) {
                    const float4 wa = *(const float4*)(wraw[ga][t] + s * 32);
                    const float4 wb = *(const float4*)(wraw[ga][t] + s * 32 + 4);
                    pack8(wa, wb, wh6[ga * 2 + t], wl6[ga * 2 + t]);
                }
            }
        }

        #pragma unroll
        for (int ga = 0; ga < 3; ++ga) {
            #pragma unroll
            for (int t = 0; t < 2; ++t) {
                const bf16x8 wh = as_bf(wh6[ga * 2 + t]);
                const bf16x8 wl = as_bf(wl6[ga * 2 + t]);
                acc[ga][t] = __builtin_amdgcn_mfma_f32_16x16x32_bf16(ah, wh, acc[ga][t], 0, 0, 0);
                acc[ga][t] = __builtin_amdgcn_mfma_f32_16x16x32_bf16(al, wh, acc[ga][t], 0, 0, 0);
                acc[ga][t] = __builtin_amdgcn_mfma_f32_16x16x32_bf16(ah, wl, acc[ga][t], 0, 0, 0);
            }
        }
    }

    // ---- in-register epilogue (C/D map: col=lane&15, row=(lane>>4)*4+r) ----
    const int l15 = lane & 15;
    const int rg  = lane >> 4;
    #pragma unroll
    for (int t = 0; t < 2; ++t) {
        const int o = wv * 32 + t * 16 + l15;

        const float bi0 = b_ih[(0 * GG + g) * OO + o];
        const float bi1 = b_ih[(1 * GG + g) * OO + o];
        const float bi2 = b_ih[(2 * GG + g) * OO + o];
        const float bh0 = b_hh[(0 * GG + g) * OO + o];
        const float bh1 = b_hh[(1 * GG + g) * OO + o];
        const float bh2 = b_hh[(2 * GG + g) * OO + o];
        const float wd0 = w_hh[((size_t)(0 * GG + g) * OO + o) * OO + o];
        const float wd1 = w_hh[((size_t)(1 * GG + g) * OO + o) * OO + o];
        const float wd2 = w_hh[((size_t)(2 * GG + g) * OO + o) * OO + o];

        #pragma unroll
        for (int r = 0; r < 4; ++r) {
            const int row = rg * 4 + r;
            const size_t idx = ((size_t)row * VV + v) * OO + o;
            const float h = hx[idx];

            const float gr  = acc[0][t][r] + bi0 + fmaf(h, wd0, bh0);
            const float gz  = acc[1][t][r] + bi1 + fmaf(h, wd1, bh1);
            const float ghn = fmaf(h, wd2, bh2);

            const float rr = 1.f / (1.f + __expf(-gr));
            const float zz = 1.f / (1.f + __expf(-gz));

            float tt = acc[2][t][r] + bi2 + rr * ghn;
            tt = fminf(fmaxf(tt, -15.f), 15.f);
            const float e2 = __expf(2.f * tt);
            const float th = (e2 - 1.f) / (e2 + 1.f);

            out[idx] = (1.f - zz) * th + zz * h;
        }
    }
}

extern "C" void kernel_launch(void* const* d_in, const int* in_sizes, int n_in,
                              void* d_out, int out_size, void* d_ws, size_t ws_size,
                              hipStream_t stream) {
    const float* x    = (const float*)d_in[0];
    const float* hx   = (const float*)d_in[1];
    const int*   gidx = (const int*)d_in[2];
    const float* w_ih = (const float*)d_in[3];
    const float* b_ih = (const float*)d_in[4];
    const float* w_hh = (const float*)d_in[5];
    const float* b_hh = (const float*)d_in[6];
    float* out = (float*)d_out;
    uint4* wp  = (uint4*)d_ws;   // 3 MB packed split-bf16 w_ih fragments

    const size_t need = 98304ull * 32ull;   // 3 MB
    if (ws_size >= need) {
        prepack_kernel<<<384, 256, 0, stream>>>(w_ih, wp);
        ggru_mfma_kernel<true><<<VV, 256, 0, stream>>>(
            x, hx, gidx, wp, w_ih, b_ih, w_hh, b_hh, out);
    } else {
        ggru_mfma_kernel<false><<<VV, 256, 0, stream>>>(
            x, hx, gidx, (const uint4*)nullptr, w_ih, b_ih, w_hh, b_hh, out);
    }
}